// Round 4
// baseline (320.787 us; speedup 1.0000x reference)
//
#include <hip/hip_runtime.h>
#include <hip/hip_bf16.h>

// PointNetConv on MI355X (gfx950) — round 11. f32 inputs.
// Algebra: h1 = relu(A[row] - P[col]),  A = x@W1x + b1 + pos@W1p,  P = pos@W1p.
//
// r10 result: 282us; pernode 142us top (VALUBusy 53, MfmaUtil 19, 0 conflicts).
// Cost model: LDS W2 re-read = 127K chunks x 32KB = 4.1GB / 52TB/s = 78us
// (dominant, CU-serial); VALU scalar bf16 relu ~130 inst/chunk; 27% of chunks
// are per-node pad-to-16 overhead.
//
// r11:
//  (1) f16 path (A/P/W2/maxbf): packed v_pk_add/max_f16 relu, mfma_..._f16,
//      better precision than bf16.
//  (2) packed stream pernode: passB emits pad-to-8 CSR stream of u32
//      (col8<<24|row24); waves take edge-balanced node-snapped ranges
//      (register binary search over startA); 16-row chunks span <=2 nodes,
//      each 8-row half single-node -> segmentation via shfl16/shfl32 + select;
//      boundary stalls gone (P prefetched per chunk like A).
//  (3) u32 pairs in passA too: half the LDS + half the pairsA traffic;
//      ws need ~29MB (< r10's 35.5MB which fit).

typedef _Float16 f16_t;
typedef _Float16 f16x8 __attribute__((ext_vector_type(8)));
typedef float    f32x4 __attribute__((ext_vector_type(4)));

#define DPAD 16
#define NSB_SHIFT 8          // 256 nodes per superbucket
#define SBCAP 9216           // passA per-bucket input cap (u32 entries)
#define SBCAP_OUT 11264      // padded stream cap: 9216 + 256*8 = 11264 exact
#define PA_TILE 2048         // edges per passA tile
#define SPB 40               // pernode wave-slots per bucket (multiple of 4)

__device__ __forceinline__ f16x8 sub_relu8(f16x8 a, f16x8 b) {
  f16x8 d = a - b;               // v_pk_add_f16 (neg)
  f16x8 z = {};
  return __builtin_elementwise_max(d, z);   // v_pk_max_f16
}

// ---------------- fallback scan chain (proven r7) ----------------
__global__ __launch_bounds__(256) void tilesum_kernel(const int* __restrict__ dpad,
                                                      int* __restrict__ tsum, int N) {
  __shared__ int ws[4];
  int tid = threadIdx.x;
  int i = blockIdx.x * 256 + tid;
  int v = (i < N) ? dpad[(long)i * DPAD] : 0;
#pragma unroll
  for (int off = 32; off > 0; off >>= 1) v += __shfl_down(v, off, 64);
  if ((tid & 63) == 0) ws[tid >> 6] = v;
  __syncthreads();
  if (tid == 0) tsum[blockIdx.x] = ws[0] + ws[1] + ws[2] + ws[3];
}

__global__ __launch_bounds__(256) void tscan_kernel(const int* __restrict__ tsum,
                                                    int* __restrict__ texcl,
                                                    int* __restrict__ startN, int nt_) {
  __shared__ int wsum[4];
  int tid = threadIdx.x, lane = tid & 63, w = tid >> 6;
  int v = (tid < nt_) ? tsum[tid] : 0;
  int s = v;
#pragma unroll
  for (int off = 1; off < 64; off <<= 1) {
    int t = __shfl_up(s, off, 64);
    if (lane >= off) s += t;
  }
  if (lane == 63) wsum[w] = s;
  __syncthreads();
  int add = 0;
  for (int j = 0; j < w; ++j) add += wsum[j];
  if (tid < nt_) texcl[tid] = add + s - v;
  if (tid == 0) *startN = wsum[0] + wsum[1] + wsum[2] + wsum[3];
}

__global__ __launch_bounds__(256) void scanout_kernel(int* __restrict__ dpad,
                                                      const int* __restrict__ texcl,
                                                      int* __restrict__ start, int N) {
  __shared__ int wsum[4];
  int tid = threadIdx.x, lane = tid & 63, w = tid >> 6;
  int i = blockIdx.x * 256 + tid;
  int v = (i < N) ? dpad[(long)i * DPAD] : 0;
  int s = v;
#pragma unroll
  for (int off = 1; off < 64; off <<= 1) {
    int t = __shfl_up(s, off, 64);
    if (lane >= off) s += t;
  }
  if (lane == 63) wsum[w] = s;
  __syncthreads();
  int add = texcl[blockIdx.x];
  for (int j = 0; j < w; ++j) add += wsum[j];
  int excl = add + s - v;
  if (i < N) { start[i] = excl; dpad[(long)i * DPAD + 8] = excl; }
}

__global__ __launch_bounds__(256) void scatter_kernel(const int* __restrict__ eidx,
                                                      int* __restrict__ dpad,
                                                      int* __restrict__ srow, int E) {
  int i = blockIdx.x * 256 + threadIdx.x;
  if (i < E) {
    int slot = atomicAdd(&dpad[(long)eidx[E + i] * DPAD + 8], 1);
    srow[slot] = eidx[i];
  }
}

__device__ __forceinline__ f16x8 load_frag8h(const float* p) {
  float4 a = *(const float4*)p;
  float4 b = *(const float4*)(p + 4);
  f16x8 r;
  r[0] = (f16_t)a.x; r[1] = (f16_t)a.y; r[2] = (f16_t)a.z; r[3] = (f16_t)a.w;
  r[4] = (f16_t)b.x; r[5] = (f16_t)b.y; r[6] = (f16_t)b.z; r[7] = (f16_t)b.w;
  return r;
}

// ---------------------------------------------------------------------------
// Shared-memory structs for the role-split kernels (union via char buffer).
// ---------------------------------------------------------------------------
struct GemmSmem {
  f16_t ws_[8][4][64][8];    // 32768 B
  float w1ps[3][128];        //  1536 B
  float bs_[128];            //   512 B
  float pos_s[64][3];        //   768 B
};                           // 35584 B

struct PassASmem {
  unsigned sorted[PA_TILE];       // 8192 B
  unsigned char sbb[PA_TILE];     // 2048 B
  int hist[256];
  int off_[256];
  int cur[256];
  int gbase[256];
  int scanb[256];
};                                // 15360 B

#define SMEM_BYTES 35840

// ---------------------------------------------------------------------------
// AP-GEMM body: A = x@W1x + b1 + pos@W1p, P = pos@W1p (f16 into d_out).
// ---------------------------------------------------------------------------
__device__ __forceinline__ void ap_gemm_body(
    const float* __restrict__ x, const float* __restrict__ pos,
    const float* __restrict__ W1, const float* __restrict__ b1,
    f16_t* __restrict__ Abuf, f16_t* __restrict__ Pbuf, int N, int blk,
    char* smem)
{
  GemmSmem* G = (GemmSmem*)smem;
  const int tid = threadIdx.x;
  for (int it = tid; it < 8 * 4 * 64; it += 256) {
    int nt = it >> 8, kt = (it >> 6) & 3, l = it & 63;
    int n = nt * 16 + (l & 15), quad = l >> 4;
    f16x8 v;
#pragma unroll
    for (int j = 0; j < 8; ++j) v[j] = (f16_t)W1[(kt * 32 + quad * 8 + j) * 128 + n];
    *(f16x8*)&G->ws_[nt][kt][l][0] = v;
  }
  for (int it = tid; it < 384; it += 256)
    G->w1ps[it >> 7][it & 127] = W1[(128 + (it >> 7)) * 128 + (it & 127)];
  if (tid < 128) G->bs_[tid] = b1[tid];
  {
    int g = blk * 192 + tid;
    if (tid < 192 && g < 3 * N) G->pos_s[tid / 3][tid % 3] = pos[g];
  }
  __syncthreads();

  const int w = tid >> 6, lane = tid & 63;
  const int m15 = lane & 15, quad = lane >> 4;

  int node_a = blk * 64 + w * 16 + m15;
  const float* xrow = x + (long)min(node_a, N - 1) * 128;
  f16x8 a[4];
#pragma unroll
  for (int kt = 0; kt < 4; ++kt)
    a[kt] = load_frag8h(xrow + kt * 32 + quad * 8);

  f32x4 acc[8];
#pragma unroll
  for (int nt = 0; nt < 8; ++nt) acc[nt] = (f32x4){0.f, 0.f, 0.f, 0.f};
#pragma unroll
  for (int nt = 0; nt < 8; ++nt)
#pragma unroll
    for (int kt = 0; kt < 4; ++kt)
      acc[nt] = __builtin_amdgcn_mfma_f32_16x16x32_f16(
          a[kt], *(const f16x8*)&G->ws_[nt][kt][lane][0], acc[nt], 0, 0, 0);

#pragma unroll
  for (int r = 0; r < 4; ++r) {
    int nl = w * 16 + quad * 4 + r;
    int node = blk * 64 + nl;
    if (node < N) {
      float p0 = G->pos_s[nl][0], p1 = G->pos_s[nl][1], p2 = G->pos_s[nl][2];
#pragma unroll
      for (int nt = 0; nt < 8; ++nt) {
        int c = nt * 16 + m15;
        float pv = p0 * G->w1ps[0][c] + p1 * G->w1ps[1][c] + p2 * G->w1ps[2][c];
        long idx = (long)node * 128 + c;
        Abuf[idx] = (f16_t)(acc[nt][r] + G->bs_[c] + pv);
        Pbuf[idx] = (f16_t)pv;
      }
    }
  }
}

// ---------------------------------------------------------------------------
// passA body: tile-sort PA_TILE edges into superbuckets, all random ops in
// LDS; ~NSB aggregated global atomics per tile; coalesced u32 segment writes.
// Entry format: (col&255)<<24 | row   (bucket id implicit in region).
// ---------------------------------------------------------------------------
__device__ __forceinline__ void passa_body(
    const int* __restrict__ eidx, unsigned* __restrict__ pairsBuf,
    int* __restrict__ superCursor, int E, int tile, char* smem)
{
  PassASmem* S = (PassASmem*)smem;
  const int tid = threadIdx.x;
  const int base = tile * PA_TILE;
  const int cnt_t = min(PA_TILE, E - base);

  for (int j = tid; j < 256; j += 256) S->hist[j] = 0;
  __syncthreads();

  int myrow[8], mycol[8];
#pragma unroll
  for (int k = 0; k < 8; ++k) {
    int idx = k * 256 + tid;
    int i = base + idx;
    if (idx < cnt_t) {
      myrow[k] = eidx[i];
      mycol[k] = eidx[E + i];
      atomicAdd(&S->hist[mycol[k] >> NSB_SHIFT], 1);
    } else mycol[k] = -1;
  }
  __syncthreads();

  int v = S->hist[tid];
  S->scanb[tid] = v;
  __syncthreads();
  for (int d = 1; d < 256; d <<= 1) {
    int t = (tid >= d) ? S->scanb[tid - d] : 0;
    __syncthreads();
    S->scanb[tid] += t;
    __syncthreads();
  }
  int excl = S->scanb[tid] - v;
  S->off_[tid] = excl;
  S->cur[tid]  = excl;
  S->gbase[tid] = (v > 0) ? atomicAdd(&superCursor[tid * 16], v) : 0;
  __syncthreads();

#pragma unroll
  for (int k = 0; k < 8; ++k) {
    if (mycol[k] >= 0) {
      int sb = mycol[k] >> NSB_SHIFT;
      int pos = atomicAdd(&S->cur[sb], 1);
      S->sorted[pos] = ((unsigned)(mycol[k] & 255) << 24) | (unsigned)myrow[k];
      S->sbb[pos] = (unsigned char)sb;
    }
  }
  __syncthreads();

#pragma unroll
  for (int k = 0; k < 8; ++k) {
    int idx = k * 256 + tid;
    if (idx < cnt_t) {
      int sb = S->sbb[idx];
      int local = idx - S->off_[sb];
      int g = S->gbase[sb] + local;
      if (g < SBCAP) pairsBuf[(long)sb * SBCAP + g] = S->sorted[idx];
    }
  }
}

// fusedA: AP-GEMM role + passA role in one launch (overlap).
__global__ __launch_bounds__(256) void fusedA_kernel(
    const float* __restrict__ x, const float* __restrict__ pos,
    const int* __restrict__ eidx, const float* __restrict__ W1,
    const float* __restrict__ b1, unsigned* __restrict__ pairsBuf,
    int* __restrict__ superCursor, f16_t* __restrict__ Abuf,
    f16_t* __restrict__ Pbuf, int N, int E, int nodeBlocks)
{
  __shared__ __align__(16) char smem[SMEM_BYTES];
  if ((int)blockIdx.x >= nodeBlocks) {
    passa_body(eidx, pairsBuf, superCursor, E, (int)blockIdx.x - nodeBlocks, smem);
    return;
  }
  ap_gemm_body(x, pos, W1, b1, Abuf, Pbuf, N, blockIdx.x, smem);
}

// Fallback path: hist role + AP-GEMM role (r7-proven).
__global__ __launch_bounds__(256) void fused_hist_kernel(
    const float* __restrict__ x, const float* __restrict__ pos,
    const int* __restrict__ eidx, const float* __restrict__ W1,
    const float* __restrict__ b1, int* __restrict__ dpad,
    f16_t* __restrict__ Abuf, f16_t* __restrict__ Pbuf,
    int N, int E, int nodeBlocks)
{
  __shared__ __align__(16) char smem[SMEM_BYTES];
  if ((int)blockIdx.x >= nodeBlocks) {
    int i = ((int)blockIdx.x - nodeBlocks) * 256 + threadIdx.x;
    if (i < E) atomicAdd(&dpad[(long)eidx[E + i] * DPAD], 1);
    return;
  }
  ap_gemm_body(x, pos, W1, b1, Abuf, Pbuf, N, blockIdx.x, smem);
}

// ---------------------------------------------------------------------------
// passB: one block per superbucket; pad-to-8 CSR stream built via LDS
// hist/scan + direct global scatter (L2-resident region). Emits:
//   rowsOut: padded stream of (col8<<24|row24), pads duplicate a real edge
//   startA[n]: absolute padded start index (monotone, incl. n>=N tails)
//   padCount[sb]: padded total per bucket (multiple of 8)
// ---------------------------------------------------------------------------
__global__ __launch_bounds__(256) void passb_kernel(
    const unsigned* __restrict__ pairsA, const int* __restrict__ superCursor,
    unsigned* __restrict__ rowsOut, int* __restrict__ startA,
    int* __restrict__ padCount, int N)
{
  __shared__ int deg[256], offp[256], cur[256], scanb[256];
  const int sb = blockIdx.x, tid = threadIdx.x;
  const int cntIn = min(superCursor[sb * 16], SBCAP);
  const unsigned* Pin = pairsA + (long)sb * SBCAP;
  unsigned* Rout = rowsOut + (long)sb * SBCAP_OUT;

  deg[tid] = 0;
  __syncthreads();
  for (int i = tid; i < cntIn; i += 256)
    atomicAdd(&deg[Pin[i] >> 24], 1);
  __syncthreads();
  int d = deg[tid];
  int dp = (d + 7) & ~7;
  scanb[tid] = dp;
  __syncthreads();
  for (int s = 1; s < 256; s <<= 1) {
    int t2 = (tid >= s) ? scanb[tid - s] : 0;
    __syncthreads();
    scanb[tid] += t2;
    __syncthreads();
  }
  int excl = scanb[tid] - dp;
  offp[tid] = excl;
  cur[tid]  = excl;
  startA[sb * 256 + tid] = sb * SBCAP_OUT + excl;
  if (tid == 255) padCount[sb] = excl + dp;
  __syncthreads();
  for (int i = tid; i < cntIn; i += 256) {
    unsigned p = Pin[i];
    int slot = atomicAdd(&cur[p >> 24], 1);
    Rout[slot] = p;
  }
  __syncthreads();
  if (d > 0) {
    unsigned fill = Rout[offp[tid]];
    for (int j = d; j < dp; ++j) Rout[offp[tid] + j] = fill;
  }
}

// ---------------------------------------------------------------------------
// pernode r11: packed-stream waves. Each wave takes an edge-balanced,
// node-snapped slice of one bucket's padded stream. 16-row chunks; the two
// 8-row halves are single-node (8-aligned segments). Per chunk: fold per-half
// col-maxes via shfl16/shfl32; uniform A+P prefetch pipeline (no boundary
// reload chain); node finish = add b2 + store (no extra shuffles).
// ---------------------------------------------------------------------------
__global__ __launch_bounds__(256) void pernode_packed_kernel(
    const f16_t* __restrict__ Abuf, const f16_t* __restrict__ Pbuf,
    const float* __restrict__ W2, const float* __restrict__ b2,
    const int* __restrict__ startA, const int* __restrict__ padCount,
    const unsigned* __restrict__ stream, f16_t* __restrict__ maxbf,
    int N, int NSB)
{
  __shared__ f16_t w2s[8][4][64][8];   // 16 KB
  __shared__ float b2s[128];

  const int tid = threadIdx.x;
  for (int it = tid; it < 8 * 4 * 64; it += 256) {
    int nt = it >> 8, kt = (it >> 6) & 3, l = it & 63;
    int ncol = nt * 16 + (l & 15), q = l >> 4;
    f16x8 v;
#pragma unroll
    for (int j = 0; j < 8; ++j) v[j] = (f16_t)W2[(kt * 32 + q * 8 + j) * 128 + ncol];
    *(f16x8*)&w2s[nt][kt][l][0] = v;
  }
  if (tid < 128) b2s[tid] = b2[tid];
  __syncthreads();

  const int w = tid >> 6, lane = tid & 63;
  const int m15 = lane & 15, quad = lane >> 4;

  const int slot = (int)blockIdx.x * 4 + w;
  const int sb = slot / SPB, sub = slot - sb * SPB;
  if (sb >= NSB) return;
  const int nbase = sb << 8;
  const int gbi = sb * SBCAP_OUT;
  const int cnt = padCount[sb];

  int nextStore, nhi;
  int eLo = 0, eHi = 0;

  if (cnt == 0) {
    int a = min(sub * 7, 256);
    nhi = min(a + 7, 256);
    nextStore = nbase + a;
  } else {
    int4 sv = *(const int4*)(startA + nbase + lane * 4);
    int r3 = sv.w - gbi;   // max of this lane's 4 (monotone)
    auto searchT = [&](int p) -> int {   // smallest t with rel(t) >= p, else 256
      unsigned long long m = __ballot(r3 >= p);
      if (m == 0ull) return 256;
      int fl = (int)__builtin_ctzll(m);
      int e0 = __shfl(sv.x, fl, 64) - gbi;
      int e1 = __shfl(sv.y, fl, 64) - gbi;
      int e2 = __shfl(sv.z, fl, 64) - gbi;
      int j = (e0 >= p) ? 0 : (e1 >= p) ? 1 : (e2 >= p) ? 2 : 3;
      return fl * 4 + j;
    };
    int nlo = searchT(sub * cnt / SPB);
    nhi = (sub == SPB - 1) ? 256 : searchT((sub + 1) * cnt / SPB);
    nextStore = nbase + nlo;
    eLo = (nlo >= 256) ? cnt : (startA[nbase + nlo] - gbi);
    eHi = (nhi >= 256) ? cnt : (startA[nbase + nhi] - gbi);
  }

  auto zerosTo = [&](int gEnd) {
    while (nextStore < gEnd) {
      if (nextStore < N && quad == 0) {
#pragma unroll
        for (int nt = 0; nt < 8; ++nt)
          maxbf[(long)nextStore * 128 + nt * 16 + m15] = (f16_t)0.f;
      }
      ++nextStore;
    }
  };

  if (eLo >= eHi) { zerosTo(nbase + nhi); return; }

  const int nchunks = (eHi - eLo + 15) >> 4;
  const int lastI = gbi + eHi - 1;
  const int baseI = gbi + eLo;

  float runmax[8], mh[8];
#pragma unroll
  for (int nt = 0; nt < 8; ++nt) runmax[nt] = -3.4e38f;
  int open = -1;

  auto storeNode = [&](int g) {
    if (g < N && quad == 0) {
#pragma unroll
      for (int nt = 0; nt < 8; ++nt)
        maxbf[(long)g * 128 + nt * 16 + m15] =
            (f16_t)(runmax[nt] + b2s[nt * 16 + m15]);
    }
  };

  // prologue: pairs for chunk 0 and 1, A/P for chunk 0
  unsigned u1 = stream[min(baseI + m15, lastI)];
  unsigned u2 = stream[min(baseI + 16 + m15, lastI)];
  int ca0 = nbase + __shfl((int)(u1 >> 24), 0, 16);
  int cb0 = nbase + __shfl((int)(u1 >> 24), 8, 16);
  int ca1 = nbase + __shfl((int)(u2 >> 24), 0, 16);
  int cb1 = nbase + __shfl((int)(u2 >> 24), 8, 16);

  f16x8 xv[4], pv[4];
  {
    long rA = (long)(u1 & 0xFFFFFFu) * 128 + quad * 8;
    long rP = (long)(nbase + (int)(u1 >> 24)) * 128 + quad * 8;
#pragma unroll
    for (int kt = 0; kt < 4; ++kt) {
      xv[kt] = *(const f16x8*)(Abuf + rA + kt * 32);
      pv[kt] = *(const f16x8*)(Pbuf + rP + kt * 32);
    }
  }

  for (int t = 0; t < nchunks; ++t) {
    // issue pair load for chunk t+2 and A/P loads for chunk t+1
    unsigned u3 = stream[min(baseI + (t + 2) * 16 + m15, lastI)];
    f16x8 xn[4], pn[4];
    {
      long rA = (long)(u2 & 0xFFFFFFu) * 128 + quad * 8;
      long rP = (long)(nbase + (int)(u2 >> 24)) * 128 + quad * 8;
#pragma unroll
      for (int kt = 0; kt < 4; ++kt) {
        xn[kt] = *(const f16x8*)(Abuf + rA + kt * 32);
        pn[kt] = *(const f16x8*)(Pbuf + rP + kt * 32);
      }
    }

    // h1 = relu(A - P), packed f16
#pragma unroll
    for (int kt = 0; kt < 4; ++kt) xv[kt] = sub_relu8(xv[kt], pv[kt]);

    // node-entry control (cols wave-uniform by construction)
    if (ca0 != open) {
      if (open >= 0) { zerosTo(open); storeNode(open); nextStore = open + 1; }
      zerosTo(ca0);
      open = ca0;
#pragma unroll
      for (int nt = 0; nt < 8; ++nt) runmax[nt] = -3.4e38f;
    }

#pragma unroll
    for (int half = 0; half < 2; ++half) {
      f32x4 a0 = (f32x4){0.f, 0.f, 0.f, 0.f}, a1 = a0, a2 = a0, a3 = a0;
#pragma unroll
      for (int kt = 0; kt < 4; ++kt) {
        a0 = __builtin_amdgcn_mfma_f32_16x16x32_f16(
            xv[kt], *(const f16x8*)&w2s[half * 4 + 0][kt][lane][0], a0, 0, 0, 0);
        a1 = __builtin_amdgcn_mfma_f32_16x16x32_f16(
            xv[kt], *(const f16x8*)&w2s[half * 4 + 1][kt][lane][0], a1, 0, 0, 0);
        a2 = __builtin_amdgcn_mfma_f32_16x16x32_f16(
            xv[kt], *(const f16x8*)&w2s[half * 4 + 2][kt][lane][0], a2, 0, 0, 0);
        a3 = __builtin_amdgcn_mfma_f32_16x16x32_f16(
            xv[kt], *(const f16x8*)&w2s[half * 4 + 3][kt][lane][0], a3, 0, 0, 0);
      }
#pragma unroll
      for (int i = 0; i < 4; ++i) {
        f32x4 acc = (i == 0) ? a0 : (i == 1) ? a1 : (i == 2) ? a2 : a3;
        float v = fmaxf(fmaxf(acc[0], acc[1]), fmaxf(acc[2], acc[3]));
        float v16 = fmaxf(v, __shfl_xor(v, 16, 64));
        float vx  = __shfl_xor(v16, 32, 64);
        float lo_ = (quad < 2) ? v16 : vx;    // this col's max over rows 0-7
        float hi_ = (quad < 2) ? vx : v16;    // ... over rows 8-15
        int nt = half * 4 + i;
        runmax[nt] = fmaxf(runmax[nt], lo_);
        mh[nt] = hi_;
      }
    }

    if (cb0 != ca0) {           // node ca0 ends at this chunk's midpoint
      zerosTo(open);
      storeNode(open);
      nextStore = open + 1;
      open = cb0;
#pragma unroll
      for (int nt = 0; nt < 8; ++nt) runmax[nt] = mh[nt];
    } else {
#pragma unroll
      for (int nt = 0; nt < 8; ++nt) runmax[nt] = fmaxf(runmax[nt], mh[nt]);
    }

    // rotate pipeline
#pragma unroll
    for (int kt = 0; kt < 4; ++kt) { xv[kt] = xn[kt]; pv[kt] = pn[kt]; }
    u2 = u3;
    ca0 = ca1; cb0 = cb1;
    ca1 = nbase + __shfl((int)(u3 >> 24), 0, 16);
    cb1 = nbase + __shfl((int)(u3 >> 24), 8, 16);
  }

  if (open >= 0) { zerosTo(open); storeNode(open); nextStore = open + 1; }
  zerosTo(nbase + nhi);
}

// ---------------------------------------------------------------------------
// pernode fallback (r9-proven structure, f16-ized): CSR start/end + srow.
// ---------------------------------------------------------------------------
__global__ __launch_bounds__(256) void pernode_kernel(
    const f16_t* __restrict__ Abuf, const f16_t* __restrict__ Pbuf,
    const float* __restrict__ W2, const float* __restrict__ b2,
    const int* __restrict__ startp, const int* __restrict__ endp,
    const int* __restrict__ srow, f16_t* __restrict__ maxbf, int N)
{
  __shared__ f16_t w2s[8][4][64][8];
  __shared__ float b2s[128];

  const int tid = threadIdx.x;
  for (int it = tid; it < 8 * 4 * 64; it += 256) {
    int nt = it >> 8, kt = (it >> 6) & 3, l = it & 63;
    int ncol = nt * 16 + (l & 15), q = l >> 4;
    f16x8 v;
#pragma unroll
    for (int j = 0; j < 8; ++j) v[j] = (f16_t)W2[(kt * 32 + q * 8 + j) * 128 + ncol];
    *(f16x8*)&w2s[nt][kt][l][0] = v;
  }
  if (tid < 128) b2s[tid] = b2[tid];
  __syncthreads();

  const int w = tid >> 6, lane = tid & 63;
  const int m15 = lane & 15, quad = lane >> 4;

  const int nslots = (int)gridDim.x * 4;
  const int slot   = (int)blockIdx.x * 4 + w;
  const int K      = (N + nslots - 1) / nslots;
  const int nBeg   = slot * K;
  const int nEnd   = min(N, nBeg + K);
  if (nBeg >= nEnd) return;

  auto adv = [&](int& n, int& c, int& e) {
    c += 16;
    if (c < e) return;
    for (;;) {
      if (++n >= nEnd) { n = nEnd; c -= 16; return; }
      int s_ = startp[n], e_ = endp[n];
      if (e_ > s_) { c = s_; e = e_; return; }
      if (quad == 0) {
#pragma unroll
        for (int nt = 0; nt < 8; ++nt)
          maxbf[(long)n * 128 + nt * 16 + m15] = (f16_t)0.f;
      }
    }
  };

  int n0 = nBeg - 1, c0 = -16, e0 = 0;
  adv(n0, c0, e0);
  if (n0 >= nEnd) return;

  f16x8 PnC[4], PnN[4];
#pragma unroll
  for (int kt = 0; kt < 4; ++kt)
    PnC[kt] = *(const f16x8*)(Pbuf + (long)n0 * 128 + kt * 32 + quad * 8);
  int r0 = srow[min(c0 + m15, e0 - 1)];

  int n1 = n0, c1 = c0, e1 = e0;
  adv(n1, c1, e1);

  f16x8 xv[4];
#pragma unroll
  for (int kt = 0; kt < 4; ++kt)
    xv[kt] = *(const f16x8*)(Abuf + (long)r0 * 128 + kt * 32 + quad * 8);

  int r1 = srow[min(c1 + m15, e1 - 1)];
#pragma unroll
  for (int kt = 0; kt < 4; ++kt) PnN[kt] = PnC[kt];
  if (n1 != n0 && n1 < nEnd) {
#pragma unroll
    for (int kt = 0; kt < 4; ++kt)
      PnN[kt] = *(const f16x8*)(Pbuf + (long)n1 * 128 + kt * 32 + quad * 8);
  }

  int n2 = n1, c2 = c1, e2 = e1;
  adv(n2, c2, e2);
  int r2 = srow[min(c2 + m15, e2 - 1)];

  float runmax[8];
#pragma unroll
  for (int nt = 0; nt < 8; ++nt) runmax[nt] = -3.4e38f;

  for (;;) {
    f16x8 xn[4];
#pragma unroll
    for (int kt = 0; kt < 4; ++kt)
      xn[kt] = *(const f16x8*)(Abuf + (long)r1 * 128 + kt * 32 + quad * 8);

#pragma unroll
    for (int kt = 0; kt < 4; ++kt) xv[kt] = sub_relu8(xv[kt], PnC[kt]);

#pragma unroll
    for (int half = 0; half < 2; ++half) {
      f32x4 a0 = (f32x4){0.f, 0.f, 0.f, 0.f}, a1 = a0, a2 = a0, a3 = a0;
#pragma unroll
      for (int kt = 0; kt < 4; ++kt) {
        a0 = __builtin_amdgcn_mfma_f32_16x16x32_f16(
            xv[kt], *(const f16x8*)&w2s[half * 4 + 0][kt][lane][0], a0, 0, 0, 0);
        a1 = __builtin_amdgcn_mfma_f32_16x16x32_f16(
            xv[kt], *(const f16x8*)&w2s[half * 4 + 1][kt][lane][0], a1, 0, 0, 0);
        a2 = __builtin_amdgcn_mfma_f32_16x16x32_f16(
            xv[kt], *(const f16x8*)&w2s[half * 4 + 2][kt][lane][0], a2, 0, 0, 0);
        a3 = __builtin_amdgcn_mfma_f32_16x16x32_f16(
            xv[kt], *(const f16x8*)&w2s[half * 4 + 3][kt][lane][0], a3, 0, 0, 0);
      }
      runmax[half * 4 + 0] = fmaxf(runmax[half * 4 + 0],
          fmaxf(fmaxf(a0[0], a0[1]), fmaxf(a0[2], a0[3])));
      runmax[half * 4 + 1] = fmaxf(runmax[half * 4 + 1],
          fmaxf(fmaxf(a1[0], a1[1]), fmaxf(a1[2], a1[3])));
      runmax[half * 4 + 2] = fmaxf(runmax[half * 4 + 2],
          fmaxf(fmaxf(a2[0], a2[1]), fmaxf(a2[2], a2[3])));
      runmax[half * 4 + 3] = fmaxf(runmax[half * 4 + 3],
          fmaxf(fmaxf(a3[0], a3[1]), fmaxf(a3[2], a3[3])));
    }

    if (n1 != n0) {
#pragma unroll
      for (int nt = 0; nt < 8; ++nt) {
        float v = runmax[nt];
        v = fmaxf(v, __shfl_xor(v, 16, 64));
        v = fmaxf(v, __shfl_xor(v, 32, 64));
        v += b2s[nt * 16 + m15];
        if (quad == 0) maxbf[(long)n0 * 128 + nt * 16 + m15] = (f16_t)v;
        runmax[nt] = -3.4e38f;
      }
#pragma unroll
      for (int kt = 0; kt < 4; ++kt) PnC[kt] = PnN[kt];
    }

    n0 = n1; c0 = c1; e0 = e1;
    if (n0 >= nEnd) break;
#pragma unroll
    for (int kt = 0; kt < 4; ++kt) xv[kt] = xn[kt];

    n1 = n2; c1 = c2; e1 = e2; r1 = r2;
    if (n1 != n0 && n1 < nEnd) {
#pragma unroll
      for (int kt = 0; kt < 4; ++kt)
        PnN[kt] = *(const f16x8*)(Pbuf + (long)n1 * 128 + kt * 32 + quad * 8);
    }

    adv(n2, c2, e2);
    r2 = srow[min(c2 + m15, e2 - 1)];
  }
}

// ---------------------------------------------------------------------------
// final: d_out = maxbf + x @ Wr + br   (f32 out)
// ---------------------------------------------------------------------------
__global__ __launch_bounds__(256) void final_gemm_kernel(
    const float* __restrict__ xin, const float* __restrict__ W,
    const float* __restrict__ bias, const f16_t* __restrict__ maxv,
    float* __restrict__ dst, int N)
{
  __shared__ f16_t ws_[8][4][64][8];
  __shared__ float bs_[128];

  const int tid = threadIdx.x;
  for (int it = tid; it < 8 * 4 * 64; it += 256) {
    int nt = it >> 8, kt = (it >> 6) & 3, l = it & 63;
    int n = nt * 16 + (l & 15), quad = l >> 4;
    f16x8 v;
#pragma unroll
    for (int j = 0; j < 8; ++j) v[j] = (f16_t)W[(kt * 32 + quad * 8 + j) * 128 + n];
    *(f16x8*)&ws_[nt][kt][l][0] = v;
  }
  if (tid < 128) bs_[tid] = bias[tid];
  __syncthreads();

  const int w = tid >> 6, lane = tid & 63;
  const int m15 = lane & 15, quad = lane >> 4;

  int node_a = blockIdx.x * 64 + w * 16 + m15;
  const float* xrow = xin + (long)min(node_a, N - 1) * 128;
  f16x8 a[4];
#pragma unroll
  for (int kt = 0; kt < 4; ++kt)
    a[kt] = load_frag8h(xrow + kt * 32 + quad * 8);

  f32x4 acc[8];
#pragma unroll
  for (int nt = 0; nt < 8; ++nt) acc[nt] = (f32x4){0.f, 0.f, 0.f, 0.f};
#pragma unroll
  for (int nt = 0; nt < 8; ++nt)
#pragma unroll
    for (int kt = 0; kt < 4; ++kt)
      acc[nt] = __builtin_amdgcn_mfma_f32_16x16x32_f16(
          a[kt], *(const f16x8*)&ws_[nt][kt][lane][0], acc[nt], 0, 0, 0);

#pragma unroll
  for (int r = 0; r < 4; ++r) {
    int node = blockIdx.x * 64 + w * 16 + quad * 4 + r;
    if (node < N) {
#pragma unroll
      for (int nt = 0; nt < 8; ++nt) {
        int c = nt * 16 + m15;
        long idx = (long)node * 128 + c;
        dst[idx] = acc[nt][r] + bs_[c] + (float)maxv[idx];
      }
    }
  }
}

extern "C" void kernel_launch(void* const* d_in, const int* in_sizes, int n_in,
                              void* d_out, int out_size, void* d_ws, size_t ws_size,
                              hipStream_t stream) {
  (void)n_in; (void)out_size;
  const float* x   = (const float*)d_in[0];
  const float* pos = (const float*)d_in[1];
  const int*   eix = (const int*)d_in[2];
  const float* W1  = (const float*)d_in[3];
  const float* b1  = (const float*)d_in[4];
  const float* W2  = (const float*)d_in[5];
  const float* b2  = (const float*)d_in[6];
  const float* Wr  = (const float*)d_in[7];
  const float* br  = (const float*)d_in[8];

  const int N = in_sizes[0] / 128;
  const int E = in_sizes[2] / 2;

  f16_t* Abuf = (f16_t*)d_out;                      // [0, N*128) f16
  f16_t* Pbuf = (f16_t*)d_out + (size_t)N * 128;    // [N*128, N*256) f16

  const int nodeBlocks = (N + 63) / 64;
  const int edgeBlocks = (E + 255) / 256;
  const int nTiles     = (N + 255) / 256;
  const int NSB        = (N + 255) >> NSB_SHIFT;
  const int paBlocks   = (E + PA_TILE - 1) / PA_TILE;

  f16_t* maxbf = (f16_t*)d_ws;                      // N*256 B

  const size_t needPack = (size_t)N * 256 + (size_t)NSB * SBCAP * 4 +
                          (size_t)NSB * SBCAP_OUT * 4 + (size_t)NSB * 256 * 4 +
                          (size_t)NSB * 4 + (size_t)NSB * 64 + 1024;

  if (ws_size >= needPack && NSB <= 256 && N < (1 << 24)) {
    // ---------------- packed-stream path ----------------
    unsigned* pairsA      = (unsigned*)((char*)d_ws + (size_t)N * 256);
    unsigned* rowsOut     = pairsA + (size_t)NSB * SBCAP;
    int*      startA      = (int*)(rowsOut + (size_t)NSB * SBCAP_OUT);
    int*      padCount    = startA + (size_t)NSB * 256;
    int*      superCursor = padCount + NSB;

    hipMemsetAsync(superCursor, 0, (size_t)NSB * 64, stream);
    fusedA_kernel<<<nodeBlocks + paBlocks, 256, 0, stream>>>(
        x, pos, eix, W1, b1, pairsA, superCursor, Abuf, Pbuf, N, E, nodeBlocks);
    passb_kernel<<<NSB, 256, 0, stream>>>(pairsA, superCursor, rowsOut,
                                          startA, padCount, N);
    pernode_packed_kernel<<<NSB * (SPB / 4), 256, 0, stream>>>(
        Abuf, Pbuf, W2, b2, startA, padCount, rowsOut, maxbf, N, NSB);
  } else {
    // ---------------- fallback: r7 hist+scan+scatter ----------------
    int* srow  = (int*)((char*)d_ws + (size_t)N * 256);
    int* dpad  = srow + E;
    int* start = dpad + (size_t)N * DPAD;
    int* tsum  = start + N + 1;
    int* texcl = tsum + 256;

    hipMemsetAsync(dpad, 0, (size_t)N * DPAD * 4, stream);
    fused_hist_kernel<<<nodeBlocks + edgeBlocks, 256, 0, stream>>>(
        x, pos, eix, W1, b1, dpad, Abuf, Pbuf, N, E, nodeBlocks);
    tilesum_kernel<<<nTiles, 256, 0, stream>>>(dpad, tsum, N);
    tscan_kernel<<<1, 256, 0, stream>>>(tsum, texcl, &start[N], nTiles);
    scanout_kernel<<<nTiles, 256, 0, stream>>>(dpad, texcl, start, N);
    scatter_kernel<<<edgeBlocks, 256, 0, stream>>>(eix, dpad, srow, E);
    pernode_kernel<<<2048, 256, 0, stream>>>(Abuf, Pbuf, W2, b2, start, start + 1,
                                             srow, maxbf, N);
  }

  final_gemm_kernel<<<nodeBlocks, 256, 0, stream>>>(x, Wr, br, maxbf,
                                                    (float*)d_out, N);
}